// Round 1
// baseline (180.480 us; speedup 1.0000x reference)
//
#include <hip/hip_runtime.h>
#include <hip/hip_bf16.h>
#include <math.h>

// Problem: B_SZ=2, L=2048, D=1024, N=16.  M = B_SZ*L = 4096.
// y[m,d] = x[m,d] * softplus((x@W1^T)[m,d] + b1[d]) * s[m]
// s[m]   = sum_n (x_m . W2_n + b2_n) * (x_m . W3_n + b3_n)
// A is unused (multiplies a zero-initialized h in the reference).

typedef __bf16 bf16x8 __attribute__((ext_vector_type(8)));
typedef __bf16 bf16x4 __attribute__((ext_vector_type(4)));
typedef float  f32x4  __attribute__((ext_vector_type(4)));

#define MDIM 4096
#define KDIM 1024
#define NDIM 1024

// ---------------- s kernel: one block per row ----------------
__global__ __launch_bounds__(256)
void s_kernel(const float* __restrict__ x,
              const float* __restrict__ W2, const float* __restrict__ b2,
              const float* __restrict__ W3, const float* __restrict__ b3,
              float* __restrict__ s) {
    __shared__ float xs[1024];
    __shared__ float ps[8][32];
    __shared__ float bc[32];
    const int m = blockIdx.x;
    const int t = threadIdx.x;

    // stage x row (1024 floats) via float4, 256 threads
    reinterpret_cast<float4*>(xs)[t] =
        reinterpret_cast<const float4*>(x + (size_t)m * 1024)[t];
    __syncthreads();

    // t = seg*32 + mat*16 + n ; seg in [0,8), mat in {0,1}, n in [0,16)
    const int n   = t & 15;
    const int mat = (t >> 4) & 1;
    const int seg = t >> 5;
    const float* __restrict__ W  = mat ? W3 : W2;
    const float* __restrict__ wr = W + (size_t)n * 1024 + seg * 128;
    const float* __restrict__ xr = xs + seg * 128;

    float p = 0.f;
#pragma unroll
    for (int i = 0; i < 128; i += 4) {
        float4 w4 = *reinterpret_cast<const float4*>(wr + i);
        float4 x4 = *reinterpret_cast<const float4*>(xr + i);
        p += w4.x * x4.x + w4.y * x4.y + w4.z * x4.z + w4.w * x4.w;
    }
    ps[seg][t & 31] = p;
    __syncthreads();

    if (t < 32) {
        float tot = 0.f;
#pragma unroll
        for (int g = 0; g < 8; ++g) tot += ps[g][t];
        tot += (t < 16) ? b2[t] : b3[t - 16];
        bc[t] = tot;
    }
    __syncthreads();

    if (t == 0) {
        float ss = 0.f;
#pragma unroll
        for (int nn = 0; nn < 16; ++nn) ss += bc[nn] * bc[16 + nn];
        s[m] = ss;
    }
}

// ---------------- fused GEMM: y = x * softplus(x@W1^T + b1) * s ----------------
// Tile: BM=128, BN=64, BK=64.  4 waves (2x2), each wave 64x32 via 4x2 MFMAs
// of v_mfma_f32_16x16x32_bf16.
#define BM 128
#define BN 64
#define BK 64
#define LDK 72  // BK + 8 bf16 pad -> row stride 144 B (16B aligned, 2-way-bank only)

__global__ __launch_bounds__(256)
void gemm_fused(const float* __restrict__ x, const float* __restrict__ W1,
                const float* __restrict__ b1, const float* __restrict__ s,
                float* __restrict__ y) {
    __shared__ __align__(16) __bf16 As[BM * LDK];
    __shared__ __align__(16) __bf16 Bs[BN * LDK];

    const int bm = blockIdx.y;   // M tile: 0..31
    const int bn = blockIdx.x;   // N tile: 0..15
    const int t = threadIdx.x;
    const int wave = t >> 6;
    const int lane = t & 63;
    const int wm = (wave >> 1) * 64;   // wave row offset in tile: 0 or 64
    const int wn = (wave & 1) * 32;    // wave col offset in tile: 0 or 32
    const int lrow = lane & 15;
    const int quad = lane >> 4;

    f32x4 acc[4][2] = {};

    // staging indices: thread t handles row (t>>4) (+16 per pass), cols (t&15)*4
    const int rbase = t >> 4;
    const int scol  = (t & 15) * 4;

    const float* __restrict__ xg = x + (size_t)(bm * BM) * KDIM + scol;
    const float* __restrict__ wg = W1 + (size_t)(bn * BN) * KDIM + scol;

    for (int k0 = 0; k0 < KDIM; k0 += BK) {
        // ---- stage A tile (128 x 64 fp32 -> bf16) ----
#pragma unroll
        for (int rr = 0; rr < 8; ++rr) {
            int row = rr * 16 + rbase;
            float4 v = *reinterpret_cast<const float4*>(xg + (size_t)row * KDIM + k0);
            bf16x4 h = { (__bf16)v.x, (__bf16)v.y, (__bf16)v.z, (__bf16)v.w };
            *reinterpret_cast<bf16x4*>(&As[row * LDK + scol]) = h;
        }
        // ---- stage B tile (64 x 64 fp32 -> bf16) ----
#pragma unroll
        for (int rr = 0; rr < 4; ++rr) {
            int row = rr * 16 + rbase;
            float4 v = *reinterpret_cast<const float4*>(wg + (size_t)row * KDIM + k0);
            bf16x4 h = { (__bf16)v.x, (__bf16)v.y, (__bf16)v.z, (__bf16)v.w };
            *reinterpret_cast<bf16x4*>(&Bs[row * LDK + scol]) = h;
        }
        __syncthreads();

#pragma unroll
        for (int kk = 0; kk < BK; kk += 32) {
            bf16x8 af[4];
            bf16x8 bfr[2];
#pragma unroll
            for (int mi = 0; mi < 4; ++mi)
                af[mi] = *reinterpret_cast<const bf16x8*>(
                    &As[(wm + mi * 16 + lrow) * LDK + kk + quad * 8]);
#pragma unroll
            for (int ni = 0; ni < 2; ++ni)
                bfr[ni] = *reinterpret_cast<const bf16x8*>(
                    &Bs[(wn + ni * 16 + lrow) * LDK + kk + quad * 8]);
#pragma unroll
            for (int mi = 0; mi < 4; ++mi)
#pragma unroll
                for (int ni = 0; ni < 2; ++ni)
                    acc[mi][ni] = __builtin_amdgcn_mfma_f32_16x16x32_bf16(
                        af[mi], bfr[ni], acc[mi][ni], 0, 0, 0);
        }
        __syncthreads();
    }

    // ---- epilogue: y = x * softplus(acc + b1) * s ----
    const int gmb = bm * BM + wm;
    const int gnb = bn * BN + wn;
#pragma unroll
    for (int ni = 0; ni < 2; ++ni) {
        const int gn = gnb + ni * 16 + lrow;
        const float bias = b1[gn];
#pragma unroll
        for (int mi = 0; mi < 4; ++mi) {
            const int gm0 = gmb + mi * 16 + quad * 4;
#pragma unroll
            for (int r = 0; r < 4; ++r) {
                const int gm = gm0 + r;
                float z = acc[mi][ni][r] + bias;
                // numerically-stable softplus
                float sp = fmaxf(z, 0.f) + log1pf(__expf(-fabsf(z)));
                y[(size_t)gm * NDIM + gn] =
                    x[(size_t)gm * NDIM + gn] * sp * s[gm];
            }
        }
    }
}

extern "C" void kernel_launch(void* const* d_in, const int* in_sizes, int n_in,
                              void* d_out, int out_size, void* d_ws, size_t ws_size,
                              hipStream_t stream) {
    const float* x  = (const float*)d_in[0];
    const float* W1 = (const float*)d_in[1];
    const float* b1 = (const float*)d_in[2];
    const float* W2 = (const float*)d_in[3];
    const float* b2 = (const float*)d_in[4];
    const float* W3 = (const float*)d_in[5];
    const float* b3 = (const float*)d_in[6];
    // d_in[7] = A : unused (multiplies zero-initialized h in the reference)

    float* s = (float*)d_ws;        // 4096 floats of scratch
    float* y = (float*)d_out;       // [2, 2048, 1024] fp32

    s_kernel<<<dim3(MDIM), dim3(256), 0, stream>>>(x, W2, b2, W3, b3, s);
    gemm_fused<<<dim3(NDIM / BN, MDIM / BM), dim3(256), 0, stream>>>(x, W1, b1, s, y);
}

// Round 2
// 135.425 us; speedup vs baseline: 1.3327x; 1.3327x over previous
//
#include <hip/hip_runtime.h>
#include <hip/hip_bf16.h>
#include <math.h>

// Problem: B_SZ=2, L=2048, D=1024, N=16.  M = B_SZ*L = 4096.
// y[m,d] = x[m,d] * softplus((x@W1^T)[m,d] + b1[d]) * s[m]
// s[m]   = sum_n (x_m . W2_n + b2_n) * (x_m . W3_n + b3_n)
// A is unused (multiplies a zero-initialized h in the reference).

typedef __bf16 bf16x8 __attribute__((ext_vector_type(8)));
typedef __bf16 bf16x4 __attribute__((ext_vector_type(4)));
typedef float  f32x4  __attribute__((ext_vector_type(4)));

#define MDIM 4096
#define KDIM 1024
#define NDIM 1024

// async global->LDS, 16B per lane; LDS dest = wave-uniform base + lane*16.
__device__ __forceinline__ void async16(const void* g, void* l) {
    __builtin_amdgcn_global_load_lds(
        (const __attribute__((address_space(1))) void*)g,
        (__attribute__((address_space(3))) void*)l, 16, 0, 0);
}

__device__ __forceinline__ float softplus_f(float z) {
    return fmaxf(z, 0.f) + log1pf(__expf(-fabsf(z)));
}

// ---------------- convert: x, W1 fp32 -> bf16 (once per call) ----------------
#define NX4 ((MDIM * KDIM) / 4)   // 1048576 float4s of x
#define NW4 ((KDIM * NDIM) / 4)   // 262144 float4s of W1
__global__ __launch_bounds__(256)
void convert_kernel(const float* __restrict__ x, const float* __restrict__ W1,
                    __bf16* __restrict__ xb, __bf16* __restrict__ w1b) {
    int i = blockIdx.x * 256 + threadIdx.x;
    if (i < NX4) {
        float4 v = reinterpret_cast<const float4*>(x)[i];
        bf16x4 h = { (__bf16)v.x, (__bf16)v.y, (__bf16)v.z, (__bf16)v.w };
        reinterpret_cast<bf16x4*>(xb)[i] = h;
    } else {
        int j = i - NX4;
        float4 v = reinterpret_cast<const float4*>(W1)[j];
        bf16x4 h = { (__bf16)v.x, (__bf16)v.y, (__bf16)v.z, (__bf16)v.w };
        reinterpret_cast<bf16x4*>(w1b)[j] = h;
    }
}

// ---------------- s kernel (MFMA): s[m] = sum_n (Bm+b2)(Cm+b3) ----------------
// Block: 256 thr = 4 waves; BM=64 rows (wave w -> rows w*16..w*16+15).
// Wc = [W2; W3] as 32 x K operand, staged fp32->bf16 per 64-k chunk.
__global__ __launch_bounds__(256)
void s_kernel_mfma(const __bf16* __restrict__ xb,
                   const float* __restrict__ W2, const float* __restrict__ b2,
                   const float* __restrict__ W3, const float* __restrict__ b3,
                   float* __restrict__ s) {
    __shared__ __align__(16) __bf16 As[64 * 64];   // 8 KB
    __shared__ __align__(16) __bf16 Ws[32 * 64];   // 4 KB
    const int t = threadIdx.x;
    const int wave = t >> 6, lane = t & 63;
    const int lrow = lane & 15, quad = lane >> 4;
    const int srow = lane >> 3, scol = (lane & 7) * 8;
    const size_t m0 = (size_t)blockIdx.x * 64;

    // W staging indices: thread t -> row t>>3 (0..31), 8 cols at (t&7)*8
    const int wrow = t >> 3;
    const int wcol = (t & 7) * 8;
    const float* __restrict__ wsrc =
        (wrow < 16) ? (W2 + (size_t)wrow * KDIM) : (W3 + (size_t)(wrow - 16) * KDIM);

    f32x4 acc[2] = {};

    for (int k0 = 0; k0 < KDIM; k0 += 64) {
        // A tile: 64x64 bf16 via async copy (8 chunks of 8 rows)
#pragma unroll
        for (int i = 0; i < 2; ++i) {
            int q = i * 4 + wave;
            int row = 8 * q + srow;
            async16(xb + (m0 + row) * KDIM + k0 + scol, &As[q * 512]);
        }
        // W tile: 32x64, fp32 -> bf16
        {
            float4 v0 = *reinterpret_cast<const float4*>(wsrc + k0 + wcol);
            float4 v1 = *reinterpret_cast<const float4*>(wsrc + k0 + wcol + 4);
            bf16x8 h = { (__bf16)v0.x, (__bf16)v0.y, (__bf16)v0.z, (__bf16)v0.w,
                         (__bf16)v1.x, (__bf16)v1.y, (__bf16)v1.z, (__bf16)v1.w };
            *reinterpret_cast<bf16x8*>(&Ws[wrow * 64 + wcol]) = h;
        }
        __syncthreads();
#pragma unroll
        for (int kk = 0; kk < 64; kk += 32) {
            bf16x8 a = *reinterpret_cast<const bf16x8*>(
                &As[(wave * 16 + lrow) * 64 + kk + quad * 8]);
#pragma unroll
            for (int ni = 0; ni < 2; ++ni) {
                bf16x8 b = *reinterpret_cast<const bf16x8*>(
                    &Ws[(ni * 16 + lrow) * 64 + kk + quad * 8]);
                acc[ni] = __builtin_amdgcn_mfma_f32_16x16x32_bf16(a, b, acc[ni], 0, 0, 0);
            }
        }
        __syncthreads();
    }

    // acc[0][r] = Bm[m, lrow], acc[1][r] = Cm[m, lrow]; m = m0 + wave*16 + quad*4 + r
    const float b2v = b2[lrow], b3v = b3[lrow];
#pragma unroll
    for (int r = 0; r < 4; ++r) {
        float p = (acc[0][r] + b2v) * (acc[1][r] + b3v);
        p += __shfl_xor(p, 1);
        p += __shfl_xor(p, 2);
        p += __shfl_xor(p, 4);
        p += __shfl_xor(p, 8);
        if (lrow == 0) s[m0 + wave * 16 + quad * 4 + r] = p;
    }
}

// ---------------- main GEMM (m97 structure): y = x * softplus(xb@W1b^T + b1) * s
#define GBM 128
#define GBN 128
#define GBK 64
__global__ __launch_bounds__(256)
void gemm_bf(const __bf16* __restrict__ xb, const __bf16* __restrict__ w1b,
             const float* __restrict__ x, const float* __restrict__ b1,
             const float* __restrict__ s, float* __restrict__ y) {
    __shared__ __align__(16) __bf16 As[GBM * GBK];  // 16 KB
    __shared__ __align__(16) __bf16 Bs[GBN * GBK];  // 16 KB
    const int bm = blockIdx.y, bn = blockIdx.x;
    const int t = threadIdx.x;
    const int wave = t >> 6, lane = t & 63;
    const int wm = (wave >> 1) * 64, wn = (wave & 1) * 64;
    const int lrow = lane & 15, quad = lane >> 4;
    const int srow = lane >> 3, scol = (lane & 7) * 8;
    const size_t m0 = (size_t)bm * GBM, n0 = (size_t)bn * GBN;

    f32x4 acc[4][4] = {};

    for (int k0 = 0; k0 < KDIM; k0 += GBK) {
#pragma unroll
        for (int i = 0; i < 4; ++i) {
            int q = i * 4 + wave;          // chunk 0..15, 8 rows each
            int row = 8 * q + srow;
            async16(xb  + (m0 + row) * KDIM + k0 + scol, &As[q * 512]);
            async16(w1b + (n0 + row) * KDIM + k0 + scol, &Bs[q * 512]);
        }
        __syncthreads();
#pragma unroll
        for (int kk = 0; kk < GBK; kk += 32) {
            bf16x8 af[4], bfr[4];
#pragma unroll
            for (int mi = 0; mi < 4; ++mi)
                af[mi] = *reinterpret_cast<const bf16x8*>(
                    &As[(wm + mi * 16 + lrow) * GBK + kk + quad * 8]);
#pragma unroll
            for (int ni = 0; ni < 4; ++ni)
                bfr[ni] = *reinterpret_cast<const bf16x8*>(
                    &Bs[(wn + ni * 16 + lrow) * GBK + kk + quad * 8]);
#pragma unroll
            for (int mi = 0; mi < 4; ++mi)
#pragma unroll
                for (int ni = 0; ni < 4; ++ni)
                    acc[mi][ni] = __builtin_amdgcn_mfma_f32_16x16x32_bf16(
                        af[mi], bfr[ni], acc[mi][ni], 0, 0, 0);
        }
        __syncthreads();
    }

    // epilogue: y = x * softplus(acc + b1) * s
#pragma unroll
    for (int ni = 0; ni < 4; ++ni) {
        const size_t gn = n0 + wn + ni * 16 + lrow;
        const float bias = b1[gn];
#pragma unroll
        for (int mi = 0; mi < 4; ++mi) {
#pragma unroll
            for (int r = 0; r < 4; ++r) {
                const size_t gm = m0 + wm + mi * 16 + quad * 4 + r;
                float z = acc[mi][ni][r] + bias;
                y[gm * NDIM + gn] = x[gm * NDIM + gn] * softplus_f(z) * s[gm];
            }
        }
    }
}

// ================= fallback path (ws too small): round-0 kernels =============
__global__ __launch_bounds__(256)
void s_kernel_fb(const float* __restrict__ x,
                 const float* __restrict__ W2, const float* __restrict__ b2,
                 const float* __restrict__ W3, const float* __restrict__ b3,
                 float* __restrict__ s) {
    __shared__ float xs[1024];
    __shared__ float ps[8][32];
    __shared__ float bc[32];
    const int m = blockIdx.x;
    const int t = threadIdx.x;
    reinterpret_cast<float4*>(xs)[t] =
        reinterpret_cast<const float4*>(x + (size_t)m * 1024)[t];
    __syncthreads();
    const int n = t & 15;
    const int mat = (t >> 4) & 1;
    const int seg = t >> 5;
    const float* __restrict__ W = mat ? W3 : W2;
    const float* __restrict__ wr = W + (size_t)n * 1024 + seg * 128;
    const float* __restrict__ xr = xs + seg * 128;
    float p = 0.f;
#pragma unroll
    for (int i = 0; i < 128; i += 4) {
        float4 w4 = *reinterpret_cast<const float4*>(wr + i);
        float4 x4 = *reinterpret_cast<const float4*>(xr + i);
        p += w4.x * x4.x + w4.y * x4.y + w4.z * x4.z + w4.w * x4.w;
    }
    ps[seg][t & 31] = p;
    __syncthreads();
    if (t < 32) {
        float tot = 0.f;
#pragma unroll
        for (int g = 0; g < 8; ++g) tot += ps[g][t];
        tot += (t < 16) ? b2[t] : b3[t - 16];
        bc[t] = tot;
    }
    __syncthreads();
    if (t == 0) {
        float ss = 0.f;
#pragma unroll
        for (int nn = 0; nn < 16; ++nn) ss += bc[nn] * bc[16 + nn];
        s[m] = ss;
    }
}

#define BM 128
#define BN 64
#define BK 64
#define LDK 72
__global__ __launch_bounds__(256)
void gemm_fused_fb(const float* __restrict__ x, const float* __restrict__ W1,
                   const float* __restrict__ b1, const float* __restrict__ s,
                   float* __restrict__ y) {
    __shared__ __align__(16) __bf16 As[BM * LDK];
    __shared__ __align__(16) __bf16 Bs[BN * LDK];
    const int bm = blockIdx.y;
    const int bn = blockIdx.x;
    const int t = threadIdx.x;
    const int wave = t >> 6;
    const int lane = t & 63;
    const int wm = (wave >> 1) * 64;
    const int wn = (wave & 1) * 32;
    const int lrow = lane & 15;
    const int quad = lane >> 4;
    f32x4 acc[4][2] = {};
    const int rbase = t >> 4;
    const int scol = (t & 15) * 4;
    const float* __restrict__ xg = x + (size_t)(bm * BM) * KDIM + scol;
    const float* __restrict__ wg = W1 + (size_t)(bn * BN) * KDIM + scol;
    for (int k0 = 0; k0 < KDIM; k0 += BK) {
#pragma unroll
        for (int rr = 0; rr < 8; ++rr) {
            int row = rr * 16 + rbase;
            float4 v = *reinterpret_cast<const float4*>(xg + (size_t)row * KDIM + k0);
            bf16x4 h = { (__bf16)v.x, (__bf16)v.y, (__bf16)v.z, (__bf16)v.w };
            *reinterpret_cast<bf16x4*>(&As[row * LDK + scol]) = h;
        }
#pragma unroll
        for (int rr = 0; rr < 4; ++rr) {
            int row = rr * 16 + rbase;
            float4 v = *reinterpret_cast<const float4*>(wg + (size_t)row * KDIM + k0);
            bf16x4 h = { (__bf16)v.x, (__bf16)v.y, (__bf16)v.z, (__bf16)v.w };
            *reinterpret_cast<bf16x4*>(&Bs[row * LDK + scol]) = h;
        }
        __syncthreads();
#pragma unroll
        for (int kk = 0; kk < BK; kk += 32) {
            bf16x8 af[4];
            bf16x8 bfr[2];
#pragma unroll
            for (int mi = 0; mi < 4; ++mi)
                af[mi] = *reinterpret_cast<const bf16x8*>(
                    &As[(wm + mi * 16 + lrow) * LDK + kk + quad * 8]);
#pragma unroll
            for (int ni = 0; ni < 2; ++ni)
                bfr[ni] = *reinterpret_cast<const bf16x8*>(
                    &Bs[(wn + ni * 16 + lrow) * LDK + kk + quad * 8]);
#pragma unroll
            for (int mi = 0; mi < 4; ++mi)
#pragma unroll
                for (int ni = 0; ni < 2; ++ni)
                    acc[mi][ni] = __builtin_amdgcn_mfma_f32_16x16x32_bf16(
                        af[mi], bfr[ni], acc[mi][ni], 0, 0, 0);
        }
        __syncthreads();
    }
    const int gmb = bm * BM + wm;
    const int gnb = bn * BN + wn;
#pragma unroll
    for (int ni = 0; ni < 2; ++ni) {
        const int gn = gnb + ni * 16 + lrow;
        const float bias = b1[gn];
#pragma unroll
        for (int mi = 0; mi < 4; ++mi) {
            const int gm0 = gmb + mi * 16 + quad * 4;
#pragma unroll
            for (int r = 0; r < 4; ++r) {
                const int gm = gm0 + r;
                float z = acc[mi][ni][r] + bias;
                y[(size_t)gm * NDIM + gn] =
                    x[(size_t)gm * NDIM + gn] * softplus_f(z) * s[gm];
            }
        }
    }
}

extern "C" void kernel_launch(void* const* d_in, const int* in_sizes, int n_in,
                              void* d_out, int out_size, void* d_ws, size_t ws_size,
                              hipStream_t stream) {
    const float* x  = (const float*)d_in[0];
    const float* W1 = (const float*)d_in[1];
    const float* b1 = (const float*)d_in[2];
    const float* W2 = (const float*)d_in[3];
    const float* b2 = (const float*)d_in[4];
    const float* W3 = (const float*)d_in[5];
    const float* b3 = (const float*)d_in[6];
    // d_in[7] = A : unused

    float* y = (float*)d_out;

    const size_t XB_BYTES = (size_t)MDIM * KDIM * 2;   // 8 MB
    const size_t WB_BYTES = (size_t)NDIM * KDIM * 2;   // 2 MB
    const size_t S_BYTES  = (size_t)MDIM * 4;          // 16 KB

    if (ws_size >= XB_BYTES + WB_BYTES + S_BYTES) {
        __bf16* xb  = (__bf16*)d_ws;
        __bf16* w1b = (__bf16*)((char*)d_ws + XB_BYTES);
        float*  s   = (float*)((char*)d_ws + XB_BYTES + WB_BYTES);
        convert_kernel<<<dim3((NX4 + NW4) / 256), dim3(256), 0, stream>>>(x, W1, xb, w1b);
        s_kernel_mfma<<<dim3(MDIM / 64), dim3(256), 0, stream>>>(xb, W2, b2, W3, b3, s);
        gemm_bf<<<dim3(NDIM / GBN, MDIM / GBM), dim3(256), 0, stream>>>(xb, w1b, x, b1, s, y);
    } else {
        float* s = (float*)d_ws;
        s_kernel_fb<<<dim3(MDIM), dim3(256), 0, stream>>>(x, W2, b2, W3, b3, s);
        gemm_fused_fb<<<dim3(NDIM / BN, MDIM / BM), dim3(256), 0, stream>>>(x, W1, b1, s, y);
    }
}

// Round 3
// 113.983 us; speedup vs baseline: 1.5834x; 1.1881x over previous
//
#include <hip/hip_runtime.h>
#include <hip/hip_bf16.h>
#include <math.h>

// Problem: B_SZ=2, L=2048, D=1024, N=16.  M = B_SZ*L = 4096.
// y[m,d] = x[m,d] * softplus((x@W1^T)[m,d] + b1[d]) * s[m]
// s[m]   = sum_n (x_m . W2_n + b2_n) * (x_m . W3_n + b3_n)
// A is unused (multiplies a zero-initialized h in the reference).

typedef __bf16 bf16x8 __attribute__((ext_vector_type(8)));
typedef __bf16 bf16x4 __attribute__((ext_vector_type(4)));
typedef float  f32x4  __attribute__((ext_vector_type(4)));

#define MDIM 4096
#define KDIM 1024
#define NDIM 1024

// async global->LDS, 16B per lane; LDS dest = wave-uniform base + lane*16.
__device__ __forceinline__ void async16(const void* g, void* l) {
    __builtin_amdgcn_global_load_lds(
        (const __attribute__((address_space(1))) void*)g,
        (__attribute__((address_space(3))) void*)l, 16, 0, 0);
}

__device__ __forceinline__ float softplus_f(float z) {
    return fmaxf(z, 0.f) + log1pf(__expf(-fabsf(z)));
}

// =================== prep: convert x,W1 -> bf16  AND  compute s ==============
// 256 blocks x 256 thr. Block b: rows m0=b*16 of x. 4 waves K-split (256 each)
// compute Bm,Cm partials via MFMA (W2/W3 fragments straight from global/L2),
// then LDS reduce -> s. W1 conversion interleaved (1024 float4 per block).
__global__ __launch_bounds__(256)
void prep_kernel(const float* __restrict__ x, const float* __restrict__ W1,
                 const float* __restrict__ W2, const float* __restrict__ b2,
                 const float* __restrict__ W3, const float* __restrict__ b3,
                 __bf16* __restrict__ xb, __bf16* __restrict__ w1b,
                 float* __restrict__ s) {
    __shared__ __align__(16) __bf16 xs[16 * 1032];   // +8 pad: conflict-free frag reads
    __shared__ float red[4][2][16][16];              // 8 KB
    const int t = threadIdx.x;
    const int wave = t >> 6, lane = t & 63;
    const int lrow = lane & 15, quad = lane >> 4;
    const size_t m0 = (size_t)blockIdx.x * 16;

    // ---- W1 slice -> bf16 (independent of the rest) ----
    {
        const float4* src = reinterpret_cast<const float4*>(W1) + (size_t)blockIdx.x * 1024;
        bf16x4* dst = reinterpret_cast<bf16x4*>(w1b) + (size_t)blockIdx.x * 1024;
#pragma unroll
        for (int i = 0; i < 4; ++i) {
            float4 v = src[i * 256 + t];
            bf16x4 h = { (__bf16)v.x, (__bf16)v.y, (__bf16)v.z, (__bf16)v.w };
            dst[i * 256 + t] = h;
        }
    }

    // ---- x rows: fp32 -> bf16, to global xb and LDS (coalesced) ----
#pragma unroll
    for (int i = 0; i < 16; ++i) {
        float4 v = *reinterpret_cast<const float4*>(x + (m0 + i) * KDIM + t * 4);
        bf16x4 h = { (__bf16)v.x, (__bf16)v.y, (__bf16)v.z, (__bf16)v.w };
        *reinterpret_cast<bf16x4*>(&xs[i * 1032 + t * 4]) = h;
        *reinterpret_cast<bf16x4*>(xb + (m0 + i) * KDIM + t * 4) = h;
    }
    __syncthreads();

    // ---- per-wave K-split MFMA: wave w covers k in [w*256, w*256+256) ----
    f32x4 acc[2] = {};
    const int wk0 = wave * 256;
#pragma unroll
    for (int ks = 0; ks < 256; ks += 32) {
        bf16x8 a = *reinterpret_cast<const bf16x8*>(
            &xs[lrow * 1032 + wk0 + ks + quad * 8]);
        {
            const float* wp = W2 + (size_t)lrow * KDIM + wk0 + ks + quad * 8;
            float4 v0 = *reinterpret_cast<const float4*>(wp);
            float4 v1 = *reinterpret_cast<const float4*>(wp + 4);
            bf16x8 b = { (__bf16)v0.x, (__bf16)v0.y, (__bf16)v0.z, (__bf16)v0.w,
                         (__bf16)v1.x, (__bf16)v1.y, (__bf16)v1.z, (__bf16)v1.w };
            acc[0] = __builtin_amdgcn_mfma_f32_16x16x32_bf16(a, b, acc[0], 0, 0, 0);
        }
        {
            const float* wp = W3 + (size_t)lrow * KDIM + wk0 + ks + quad * 8;
            float4 v0 = *reinterpret_cast<const float4*>(wp);
            float4 v1 = *reinterpret_cast<const float4*>(wp + 4);
            bf16x8 b = { (__bf16)v0.x, (__bf16)v0.y, (__bf16)v0.z, (__bf16)v0.w,
                         (__bf16)v1.x, (__bf16)v1.y, (__bf16)v1.z, (__bf16)v1.w };
            acc[1] = __builtin_amdgcn_mfma_f32_16x16x32_bf16(a, b, acc[1], 0, 0, 0);
        }
    }
    // D layout: row = quad*4 + r, col = lrow
#pragma unroll
    for (int r = 0; r < 4; ++r) {
        red[wave][0][quad * 4 + r][lrow] = acc[0][r];
        red[wave][1][quad * 4 + r][lrow] = acc[1][r];
    }
    __syncthreads();

    // ---- reduce: thread t -> (row = t>>4, n = t&15) ----
    {
        const int row = t >> 4, n = t & 15;
        float Bv = red[0][0][row][n] + red[1][0][row][n]
                 + red[2][0][row][n] + red[3][0][row][n] + b2[n];
        float Cv = red[0][1][row][n] + red[1][1][row][n]
                 + red[2][1][row][n] + red[3][1][row][n] + b3[n];
        float p = Bv * Cv;
        p += __shfl_xor(p, 1);
        p += __shfl_xor(p, 2);
        p += __shfl_xor(p, 4);
        p += __shfl_xor(p, 8);
        if (n == 0) s[m0 + row] = p;
    }
}

// =================== main GEMM: y = x * softplus(xb@w1b^T + b1) * s ==========
// 128x64x64 tiles -> 512 blocks (2/CU). XOR-swizzled LDS (conflict-free b128).
#define GBM 128
#define GBN 64
#define GBK 64
__global__ __launch_bounds__(256)
void gemm_bf(const __bf16* __restrict__ xb, const __bf16* __restrict__ w1b,
             const float* __restrict__ x, const float* __restrict__ b1,
             const float* __restrict__ s, float* __restrict__ y) {
    __shared__ __align__(16) __bf16 As[GBM * GBK];  // 16 KB
    __shared__ __align__(16) __bf16 Bs[GBN * GBK];  // 8 KB
    const int bm = blockIdx.y, bn = blockIdx.x;
    const int t = threadIdx.x;
    const int wave = t >> 6, lane = t & 63;
    const int wm = (wave >> 1) * 64, wn = (wave & 1) * 32;
    const int lrow = lane & 15, quad = lane >> 4;
    const int srow = lane >> 3;                 // row within 8-row chunk
    const int scol = ((lane & 7) ^ srow) * 8;   // XOR-swizzled source col group
    const size_t m0 = (size_t)bm * GBM, n0 = (size_t)bn * GBN;

    f32x4 acc[4][2] = {};

    for (int k0 = 0; k0 < KDIM; k0 += GBK) {
#pragma unroll
        for (int i = 0; i < 4; ++i) {
            int q = i * 4 + wave;              // A chunks 0..15 (8 rows each)
            int row = 8 * q + srow;
            async16(xb + (m0 + row) * KDIM + k0 + scol, &As[q * 512]);
        }
#pragma unroll
        for (int i = 0; i < 2; ++i) {
            int q = i * 4 + wave;              // B chunks 0..7
            int row = 8 * q + srow;
            async16(w1b + (n0 + row) * KDIM + k0 + scol, &Bs[q * 512]);
        }
        __syncthreads();

#pragma unroll
        for (int kk = 0; kk < GBK; kk += 32) {
            const int cg = (kk >> 3) + quad;   // logical col group 0..7
            bf16x8 af[4], bfr[2];
#pragma unroll
            for (int mi = 0; mi < 4; ++mi) {
                int row = wm + mi * 16 + lrow;
                af[mi] = *reinterpret_cast<const bf16x8*>(
                    &As[row * 64 + ((cg ^ (row & 7)) << 3)]);
            }
#pragma unroll
            for (int ni = 0; ni < 2; ++ni) {
                int row = wn + ni * 16 + lrow;
                bfr[ni] = *reinterpret_cast<const bf16x8*>(
                    &Bs[row * 64 + ((cg ^ (row & 7)) << 3)]);
            }
#pragma unroll
            for (int mi = 0; mi < 4; ++mi)
#pragma unroll
                for (int ni = 0; ni < 2; ++ni)
                    acc[mi][ni] = __builtin_amdgcn_mfma_f32_16x16x32_bf16(
                        af[mi], bfr[ni], acc[mi][ni], 0, 0, 0);
        }
        __syncthreads();
    }

    // ---- epilogue: y = x * softplus(acc + b1) * s ----
#pragma unroll
    for (int ni = 0; ni < 2; ++ni) {
        const size_t gn = n0 + wn + ni * 16 + lrow;
        const float bias = b1[gn];
#pragma unroll
        for (int mi = 0; mi < 4; ++mi) {
#pragma unroll
            for (int r = 0; r < 4; ++r) {
                const size_t gm = m0 + wm + mi * 16 + quad * 4 + r;
                float z = acc[mi][ni][r] + bias;
                y[gm * NDIM + gn] = x[gm * NDIM + gn] * softplus_f(z) * s[gm];
            }
        }
    }
}

// ================= fallback path (ws too small): round-0 kernels =============
__global__ __launch_bounds__(256)
void s_kernel_fb(const float* __restrict__ x,
                 const float* __restrict__ W2, const float* __restrict__ b2,
                 const float* __restrict__ W3, const float* __restrict__ b3,
                 float* __restrict__ s) {
    __shared__ float xs[1024];
    __shared__ float ps[8][32];
    __shared__ float bc[32];
    const int m = blockIdx.x;
    const int t = threadIdx.x;
    reinterpret_cast<float4*>(xs)[t] =
        reinterpret_cast<const float4*>(x + (size_t)m * 1024)[t];
    __syncthreads();
    const int n = t & 15;
    const int mat = (t >> 4) & 1;
    const int seg = t >> 5;
    const float* __restrict__ W = mat ? W3 : W2;
    const float* __restrict__ wr = W + (size_t)n * 1024 + seg * 128;
    const float* __restrict__ xr = xs + seg * 128;
    float p = 0.f;
#pragma unroll
    for (int i = 0; i < 128; i += 4) {
        float4 w4 = *reinterpret_cast<const float4*>(wr + i);
        float4 x4 = *reinterpret_cast<const float4*>(xr + i);
        p += w4.x * x4.x + w4.y * x4.y + w4.z * x4.z + w4.w * x4.w;
    }
    ps[seg][t & 31] = p;
    __syncthreads();
    if (t < 32) {
        float tot = 0.f;
#pragma unroll
        for (int g = 0; g < 8; ++g) tot += ps[g][t];
        tot += (t < 16) ? b2[t] : b3[t - 16];
        bc[t] = tot;
    }
    __syncthreads();
    if (t == 0) {
        float ss = 0.f;
#pragma unroll
        for (int nn = 0; nn < 16; ++nn) ss += bc[nn] * bc[16 + nn];
        s[m] = ss;
    }
}

#define BM 128
#define BN 64
#define BK 64
#define LDK 72
__global__ __launch_bounds__(256)
void gemm_fused_fb(const float* __restrict__ x, const float* __restrict__ W1,
                   const float* __restrict__ b1, const float* __restrict__ s,
                   float* __restrict__ y) {
    __shared__ __align__(16) __bf16 As[BM * LDK];
    __shared__ __align__(16) __bf16 Bs[BN * LDK];
    const int bm = blockIdx.y;
    const int bn = blockIdx.x;
    const int t = threadIdx.x;
    const int wave = t >> 6;
    const int lane = t & 63;
    const int wm = (wave >> 1) * 64;
    const int wn = (wave & 1) * 32;
    const int lrow = lane & 15;
    const int quad = lane >> 4;
    f32x4 acc[4][2] = {};
    const int rbase = t >> 4;
    const int scol = (t & 15) * 4;
    const float* __restrict__ xg = x + (size_t)(bm * BM) * KDIM + scol;
    const float* __restrict__ wg = W1 + (size_t)(bn * BN) * KDIM + scol;
    for (int k0 = 0; k0 < KDIM; k0 += BK) {
#pragma unroll
        for (int rr = 0; rr < 8; ++rr) {
            int row = rr * 16 + rbase;
            float4 v = *reinterpret_cast<const float4*>(xg + (size_t)row * KDIM + k0);
            bf16x4 h = { (__bf16)v.x, (__bf16)v.y, (__bf16)v.z, (__bf16)v.w };
            *reinterpret_cast<bf16x4*>(&As[row * LDK + scol]) = h;
        }
#pragma unroll
        for (int rr = 0; rr < 4; ++rr) {
            int row = rr * 16 + rbase;
            float4 v = *reinterpret_cast<const float4*>(wg + (size_t)row * KDIM + k0);
            bf16x4 h = { (__bf16)v.x, (__bf16)v.y, (__bf16)v.z, (__bf16)v.w };
            *reinterpret_cast<bf16x4*>(&Bs[row * LDK + scol]) = h;
        }
        __syncthreads();
#pragma unroll
        for (int kk = 0; kk < BK; kk += 32) {
            bf16x8 af[4];
            bf16x8 bfr[2];
#pragma unroll
            for (int mi = 0; mi < 4; ++mi)
                af[mi] = *reinterpret_cast<const bf16x8*>(
                    &As[(wm + mi * 16 + lrow) * LDK + kk + quad * 8]);
#pragma unroll
            for (int ni = 0; ni < 2; ++ni)
                bfr[ni] = *reinterpret_cast<const bf16x8*>(
                    &Bs[(wn + ni * 16 + lrow) * LDK + kk + quad * 8]);
#pragma unroll
            for (int mi = 0; mi < 4; ++mi)
#pragma unroll
                for (int ni = 0; ni < 2; ++ni)
                    acc[mi][ni] = __builtin_amdgcn_mfma_f32_16x16x32_bf16(
                        af[mi], bfr[ni], acc[mi][ni], 0, 0, 0);
        }
        __syncthreads();
    }
    const int gmb = bm * BM + wm;
    const int gnb = bn * BN + wn;
#pragma unroll
    for (int ni = 0; ni < 2; ++ni) {
        const int gn = gnb + ni * 16 + lrow;
        const float bias = b1[gn];
#pragma unroll
        for (int mi = 0; mi < 4; ++mi) {
            const int gm0 = gmb + mi * 16 + quad * 4;
#pragma unroll
            for (int r = 0; r < 4; ++r) {
                const int gm = gm0 + r;
                float z = acc[mi][ni][r] + bias;
                y[(size_t)gm * NDIM + gn] =
                    x[(size_t)gm * NDIM + gn] * softplus_f(z) * s[gm];
            }
        }
    }
}

extern "C" void kernel_launch(void* const* d_in, const int* in_sizes, int n_in,
                              void* d_out, int out_size, void* d_ws, size_t ws_size,
                              hipStream_t stream) {
    const float* x  = (const float*)d_in[0];
    const float* W1 = (const float*)d_in[1];
    const float* b1 = (const float*)d_in[2];
    const float* W2 = (const float*)d_in[3];
    const float* b2 = (const float*)d_in[4];
    const float* W3 = (const float*)d_in[5];
    const float* b3 = (const float*)d_in[6];
    // d_in[7] = A : unused

    float* y = (float*)d_out;

    const size_t XB_BYTES = (size_t)MDIM * KDIM * 2;   // 8 MB
    const size_t WB_BYTES = (size_t)NDIM * KDIM * 2;   // 2 MB
    const size_t S_BYTES  = (size_t)MDIM * 4;          // 16 KB

    if (ws_size >= XB_BYTES + WB_BYTES + S_BYTES) {
        __bf16* xb  = (__bf16*)d_ws;
        __bf16* w1b = (__bf16*)((char*)d_ws + XB_BYTES);
        float*  s   = (float*)((char*)d_ws + XB_BYTES + WB_BYTES);
        prep_kernel<<<dim3(MDIM / 16), dim3(256), 0, stream>>>(
            x, W1, W2, b2, W3, b3, xb, w1b, s);
        gemm_bf<<<dim3(NDIM / GBN, MDIM / GBM), dim3(256), 0, stream>>>(
            xb, w1b, x, b1, s, y);
    } else {
        float* s = (float*)d_ws;
        s_kernel_fb<<<dim3(MDIM), dim3(256), 0, stream>>>(x, W2, b2, W3, b3, s);
        gemm_fused_fb<<<dim3(NDIM / BN, MDIM / BM), dim3(256), 0, stream>>>(x, W1, b1, s, y);
    }
}